// Round 1
// baseline (171.957 us; speedup 1.0000x reference)
//
#include <hip/hip_runtime.h>
#include <math.h>

#define FFN_DIM 4096
#define TOKS_PER_BLOCK 64
#define NWAVES 4

// Pre-kernel: transpose W2 [8][4096] -> W2t [4096][8] so the main loop reads
// both weight streams as contiguous float4 pairs with wave-uniform addresses.
__global__ void w2_transpose_kernel(const float* __restrict__ w2,
                                    float* __restrict__ w2t) {
    int i = blockIdx.x * 256 + threadIdx.x;
    if (i < 8 * FFN_DIM) {
        int e = i >> 12;             // i / 4096
        int f = i & (FFN_DIM - 1);   // i % 4096
        w2t[f * 8 + e] = w2[i];
    }
}

// One lane = one token (both dot-product reductions stay lane-local).
// Block = 256 threads = 64 tokens; each of the 4 waves handles 1024 f-values,
// partials combined through LDS. f-loop is wave-uniform -> scalar loads.
__global__ __launch_bounds__(256, 4) void ffq_kernel(
    const float* __restrict__ x,
    const float* __restrict__ theta,
    const float* __restrict__ w1,    // [FFN][8]
    const float* __restrict__ b1,    // [FFN]
    const float* __restrict__ w2t,   // [FFN][8] (if use_w2t)
    const float* __restrict__ w2,    // [8][FFN] (fallback)
    const float* __restrict__ b2,    // [8]
    float* __restrict__ out,         // [n_tok][8]
    int n_tok, int use_w2t)
{
    __shared__ float part[NWAVES][TOKS_PER_BLOCK][9]; // +1 pad: no bank conflict

    const int tid  = threadIdx.x;
    const int lane = tid & 63;
    const int wave = __builtin_amdgcn_readfirstlane(tid >> 6);

    const int tok  = blockIdx.x * TOKS_PER_BLOCK + lane;
    const int rtok = tok < n_tok ? tok : n_tok - 1;  // clamp for tail safety

    const float cth = cosf(theta[0]);

    const float4* xv = reinterpret_cast<const float4*>(x + (size_t)rtok * 8);
    float4 x0 = xv[0];
    float4 x1 = xv[1];
    float q[8];
    q[0] = cth * cosf(x0.x); q[1] = cth * cosf(x0.y);
    q[2] = cth * cosf(x0.z); q[3] = cth * cosf(x0.w);
    q[4] = cth * cosf(x1.x); q[5] = cth * cosf(x1.y);
    q[6] = cth * cosf(x1.z); q[7] = cth * cosf(x1.w);

    float acc[8];
    #pragma unroll
    for (int e = 0; e < 8; ++e) acc[e] = 0.0f;

    const int f0 = wave * (FFN_DIM / NWAVES);
    const int f1 = f0 + (FFN_DIM / NWAVES);

    if (use_w2t) {
        #pragma unroll 4
        for (int f = f0; f < f1; ++f) {
            const float4* w1r = reinterpret_cast<const float4*>(w1 + (size_t)f * 8);
            float4 u0 = w1r[0];
            float4 u1 = w1r[1];
            float h = b1[f];
            h = fmaf(u0.x, q[0], h); h = fmaf(u0.y, q[1], h);
            h = fmaf(u0.z, q[2], h); h = fmaf(u0.w, q[3], h);
            h = fmaf(u1.x, q[4], h); h = fmaf(u1.y, q[5], h);
            h = fmaf(u1.z, q[6], h); h = fmaf(u1.w, q[7], h);
            h = fmaxf(h, 0.0f);
            const float4* w2r = reinterpret_cast<const float4*>(w2t + (size_t)f * 8);
            float4 v0 = w2r[0];
            float4 v1 = w2r[1];
            acc[0] = fmaf(h, v0.x, acc[0]); acc[1] = fmaf(h, v0.y, acc[1]);
            acc[2] = fmaf(h, v0.z, acc[2]); acc[3] = fmaf(h, v0.w, acc[3]);
            acc[4] = fmaf(h, v1.x, acc[4]); acc[5] = fmaf(h, v1.y, acc[5]);
            acc[6] = fmaf(h, v1.z, acc[6]); acc[7] = fmaf(h, v1.w, acc[7]);
        }
    } else {
        #pragma unroll 2
        for (int f = f0; f < f1; ++f) {
            const float4* w1r = reinterpret_cast<const float4*>(w1 + (size_t)f * 8);
            float4 u0 = w1r[0];
            float4 u1 = w1r[1];
            float h = b1[f];
            h = fmaf(u0.x, q[0], h); h = fmaf(u0.y, q[1], h);
            h = fmaf(u0.z, q[2], h); h = fmaf(u0.w, q[3], h);
            h = fmaf(u1.x, q[4], h); h = fmaf(u1.y, q[5], h);
            h = fmaf(u1.z, q[6], h); h = fmaf(u1.w, q[7], h);
            h = fmaxf(h, 0.0f);
            #pragma unroll
            for (int e = 0; e < 8; ++e)
                acc[e] = fmaf(h, w2[e * FFN_DIM + f], acc[e]);
        }
    }

    #pragma unroll
    for (int e = 0; e < 8; ++e) part[wave][lane][e] = acc[e];
    __syncthreads();

    // 512 outputs per block, 256 threads -> 2 each
    for (int i = tid; i < TOKS_PER_BLOCK * 8; i += 256) {
        int t = i >> 3;
        int e = i & 7;
        int gt = blockIdx.x * TOKS_PER_BLOCK + t;
        if (gt < n_tok) {
            float s = part[0][t][e] + part[1][t][e] + part[2][t][e]
                    + part[3][t][e] + b2[e];
            out[(size_t)gt * 8 + e] = s;
        }
    }
}

extern "C" void kernel_launch(void* const* d_in, const int* in_sizes, int n_in,
                              void* d_out, int out_size, void* d_ws, size_t ws_size,
                              hipStream_t stream) {
    const float* x     = (const float*)d_in[0];
    const float* theta = (const float*)d_in[1];
    const float* w1    = (const float*)d_in[2];
    const float* b1    = (const float*)d_in[3];
    const float* w2    = (const float*)d_in[4];
    const float* b2    = (const float*)d_in[5];
    float* out = (float*)d_out;

    const int n_tok = out_size / 8;                    // 65536
    float* w2t = (float*)d_ws;
    const int use_w2t =
        (ws_size >= (size_t)(8 * FFN_DIM) * sizeof(float)) ? 1 : 0;
    if (use_w2t) {
        w2_transpose_kernel<<<(8 * FFN_DIM + 255) / 256, 256, 0, stream>>>(w2, w2t);
    }
    const int grid = (n_tok + TOKS_PER_BLOCK - 1) / TOKS_PER_BLOCK;
    ffq_kernel<<<grid, 256, 0, stream>>>(x, theta, w1, b1, w2t, w2, b2, out,
                                         n_tok, use_w2t);
}

// Round 7
// 74.949 us; speedup vs baseline: 2.2943x; 2.2943x over previous
//
#include <hip/hip_runtime.h>
#include <math.h>

#define FFN_DIM 4096
#define NCHUNK  128   // 4096 / 32

typedef _Float16 f16x8 __attribute__((ext_vector_type(8)));
typedef __fp16   h16x2 __attribute__((ext_vector_type(2)));
typedef float    f32x16 __attribute__((ext_vector_type(16)));
typedef float    f32x4  __attribute__((ext_vector_type(4)));

// ---------------------------------------------------------------------------
// Pre-kernel: build fp16 MFMA fragment tables in workspace.
//  w1f  [128][64][8] f16 (128KB): lanes 0-31 = W1 rows (k=0..7); lanes 32-63 =
//        {b1, 0,...} so the constant-1 column of q^T adds the bias (k=8).
//  w2f  [128][2][16][8] f16 (64KB): W2 rows permuted so GEMM1's C/D register
//        order feeds GEMM2's B operand directly: k -> f = (k&3)+8*((k>>2)&1)+4*(k>>3)
// ---------------------------------------------------------------------------
__global__ void build_frags_kernel(const float* __restrict__ w1,
                                   const float* __restrict__ b1,
                                   const float* __restrict__ w2,
                                   _Float16* __restrict__ w1f,
                                   _Float16* __restrict__ w2f) {
    int i = blockIdx.x * 256 + threadIdx.x;
    if (i < NCHUNK * 64 * 8) {              // 65536
        int j    = i & 7;
        int lane = (i >> 3) & 63;
        int cc   = i >> 9;
        _Float16 v;
        if (lane < 32) v = (_Float16)w1[(cc * 32 + lane) * 8 + j];
        else           v = (j == 0) ? (_Float16)b1[cc * 32 + (lane & 31)]
                                    : (_Float16)0.0f;
        w1f[i] = v;
    }
    if (i < NCHUNK * 2 * 16 * 8) {          // 32768
        int j  = i & 7;
        int ci = (i >> 3) & 15;
        int c  = (i >> 7) & 1;
        int cc = i >> 8;
        int g = ci >> 3, e = ci & 7;
        int k = 8 * g + j;
        int fl = (k & 3) + 8 * ((k >> 2) & 1) + 4 * (k >> 3);
        int f = 32 * cc + 16 * c + fl;
        w2f[i] = (_Float16)w2[e * FFN_DIM + f];
    }
}

// ---------------------------------------------------------------------------
// Fused MFMA kernel. One wave = one 32-token tile; block = 4 waves = 128 tok.
// GEMM1 (swapped): D1'[f32][tok32] = W1chunk x q^T   (K=16: 8 real + bias col)
// GEMM2 (swapped): D2'[e32][tok32] += W2perm x h^T   (K=16 per half-chunk)
// h never leaves registers; no LDS; no cross-lane ops.
// ---------------------------------------------------------------------------
__global__ __launch_bounds__(256) void ffq_mfma_kernel(
    const float* __restrict__ x,
    const float* __restrict__ theta,
    const _Float16* __restrict__ w1f,   // [128][64][8]
    const _Float16* __restrict__ w2f,   // [128][2][16][8]
    const float* __restrict__ b2,
    float* __restrict__ out,
    int n_tok)
{
    const int tid  = threadIdx.x;
    const int lane = tid & 63;
    const int wave = tid >> 6;
    const int l31  = lane & 31;
    const int g    = lane >> 5;

    const int tb = (blockIdx.x * 4 + wave) * 32;
    const float cth = cosf(theta[0]);

    // ---- B1 operand: q^T fragment (col = token = lane&31) ----
    f16x8 bq = {};
    if (g == 0) {
        int tok = tb + l31;
        int rt = tok < n_tok ? tok : (n_tok - 1);
        const f32x4* xp = (const f32x4*)(x + (size_t)rt * 8);
        f32x4 x0 = xp[0], x1 = xp[1];
        bq[0] = (_Float16)(cth * cosf(x0.x));
        bq[1] = (_Float16)(cth * cosf(x0.y));
        bq[2] = (_Float16)(cth * cosf(x0.z));
        bq[3] = (_Float16)(cth * cosf(x0.w));
        bq[4] = (_Float16)(cth * cosf(x1.x));
        bq[5] = (_Float16)(cth * cosf(x1.y));
        bq[6] = (_Float16)(cth * cosf(x1.z));
        bq[7] = (_Float16)(cth * cosf(x1.w));
    } else {
        bq[0] = (_Float16)1.0f;   // k=8 column: multiplies the b1 row of W1frag
    }

    f32x16 acc = {};
    const f32x16 zero16 = {};

    const bool a2on = (l31 < 8);
    const int  ci   = g * 8 + (lane & 7);
    const _Float16* a1p = w1f + (size_t)lane * 8;   // + cc*512
    const _Float16* a2p = w2f + (size_t)ci * 8;     // + cc*256 (+128 for half c=1)

    f16x8 A1 = *(const f16x8*)a1p;
    f16x8 A2a = {}, A2b = {};
    if (a2on) {
        A2a = *(const f16x8*)(a2p);
        A2b = *(const f16x8*)(a2p + 128);
    }

    union U8 { f16x8 v; h16x2 p[4]; };

    for (int cc = 0; cc < NCHUNK; ++cc) {
        // prefetch next chunk's fragments
        f16x8 nA1 = {}, nA2a = {}, nA2b = {};
        if (cc + 1 < NCHUNK) {
            nA1 = *(const f16x8*)(a1p + (size_t)(cc + 1) * 512);
            if (a2on) {
                nA2a = *(const f16x8*)(a2p + (size_t)(cc + 1) * 256);
                nA2b = *(const f16x8*)(a2p + (size_t)(cc + 1) * 256 + 128);
            }
        }

        // GEMM1: h-tile (32 f x 32 tok), bias folded in via k=8
        f32x16 d1 = __builtin_amdgcn_mfma_f32_32x32x16_f16(A1, bq, zero16, 0, 0, 0);

        // relu + pack to fp16; register order already matches GEMM2's B layout
        U8 ua, ub;
        #pragma unroll
        for (int v = 0; v < 4; ++v) {
            ua.p[v] = __builtin_amdgcn_cvt_pkrtz(fmaxf(d1[2 * v], 0.0f),
                                                 fmaxf(d1[2 * v + 1], 0.0f));
            ub.p[v] = __builtin_amdgcn_cvt_pkrtz(fmaxf(d1[8 + 2 * v], 0.0f),
                                                 fmaxf(d1[8 + 2 * v + 1], 0.0f));
        }

        // GEMM2: two K=16 halves of the 32-f chunk
        acc = __builtin_amdgcn_mfma_f32_32x32x16_f16(A2a, ua.v, acc, 0, 0, 0);
        acc = __builtin_amdgcn_mfma_f32_32x32x16_f16(A2b, ub.v, acc, 0, 0, 0);

        A1 = nA1; A2a = nA2a; A2b = nA2b;
    }

    // rows e = 4g + r live in acc[0..3]; rows e>=8 are structurally zero
    f32x4 bv = *(const f32x4*)(b2 + 4 * g);
    int tok = tb + l31;
    if (tok < n_tok) {
        f32x4 o;
        o.x = acc[0] + bv.x;
        o.y = acc[1] + bv.y;
        o.z = acc[2] + bv.z;
        o.w = acc[3] + bv.w;
        *(f32x4*)(out + (size_t)tok * 8 + 4 * g) = o;
    }
}

// ---------------------------------------------------------------------------
// Fallback (ws too small): round-1 fp32 VALU kernel, direct w2 reads.
// ---------------------------------------------------------------------------
__global__ __launch_bounds__(256, 4) void ffq_valu_kernel(
    const float* __restrict__ x, const float* __restrict__ theta,
    const float* __restrict__ w1, const float* __restrict__ b1,
    const float* __restrict__ w2, const float* __restrict__ b2,
    float* __restrict__ out, int n_tok)
{
    __shared__ float part[4][64][9];
    const int tid = threadIdx.x;
    const int lane = tid & 63;
    const int wave = __builtin_amdgcn_readfirstlane(tid >> 6);
    const int tok = blockIdx.x * 64 + lane;
    const int rtok = tok < n_tok ? tok : n_tok - 1;
    const float cth = cosf(theta[0]);
    const f32x4* xv = (const f32x4*)(x + (size_t)rtok * 8);
    f32x4 x0 = xv[0], x1 = xv[1];
    float q[8];
    q[0]=cth*cosf(x0.x); q[1]=cth*cosf(x0.y); q[2]=cth*cosf(x0.z); q[3]=cth*cosf(x0.w);
    q[4]=cth*cosf(x1.x); q[5]=cth*cosf(x1.y); q[6]=cth*cosf(x1.z); q[7]=cth*cosf(x1.w);
    float acc[8];
    #pragma unroll
    for (int e = 0; e < 8; ++e) acc[e] = 0.0f;
    const int f0 = wave * (FFN_DIM / 4), f1 = f0 + (FFN_DIM / 4);
    #pragma unroll 2
    for (int f = f0; f < f1; ++f) {
        const f32x4* w1r = (const f32x4*)(w1 + (size_t)f * 8);
        f32x4 u0 = w1r[0], u1 = w1r[1];
        float h = b1[f];
        h = fmaf(u0.x,q[0],h); h = fmaf(u0.y,q[1],h); h = fmaf(u0.z,q[2],h); h = fmaf(u0.w,q[3],h);
        h = fmaf(u1.x,q[4],h); h = fmaf(u1.y,q[5],h); h = fmaf(u1.z,q[6],h); h = fmaf(u1.w,q[7],h);
        h = fmaxf(h, 0.0f);
        #pragma unroll
        for (int e = 0; e < 8; ++e) acc[e] = fmaf(h, w2[e * FFN_DIM + f], acc[e]);
    }
    #pragma unroll
    for (int e = 0; e < 8; ++e) part[wave][lane][e] = acc[e];
    __syncthreads();
    for (int i = tid; i < 64 * 8; i += 256) {
        int t = i >> 3, e = i & 7;
        int gt = blockIdx.x * 64 + t;
        if (gt < n_tok)
            out[(size_t)gt * 8 + e] = part[0][t][e] + part[1][t][e]
                                    + part[2][t][e] + part[3][t][e] + b2[e];
    }
}

extern "C" void kernel_launch(void* const* d_in, const int* in_sizes, int n_in,
                              void* d_out, int out_size, void* d_ws, size_t ws_size,
                              hipStream_t stream) {
    const float* x     = (const float*)d_in[0];
    const float* theta = (const float*)d_in[1];
    const float* w1    = (const float*)d_in[2];
    const float* b1    = (const float*)d_in[3];
    const float* w2    = (const float*)d_in[4];
    const float* b2    = (const float*)d_in[5];
    float* out = (float*)d_out;
    const int n_tok = out_size / 8;

    const size_t W1F_BYTES = (size_t)NCHUNK * 64 * 8 * sizeof(_Float16);  // 128KB
    const size_t W2F_BYTES = (size_t)NCHUNK * 2 * 16 * 8 * sizeof(_Float16); // 64KB

    if (ws_size >= W1F_BYTES + W2F_BYTES) {
        _Float16* w1f = (_Float16*)d_ws;
        _Float16* w2f = (_Float16*)((char*)d_ws + W1F_BYTES);
        build_frags_kernel<<<(NCHUNK * 64 * 8 + 255) / 256, 256, 0, stream>>>(
            w1, b1, w2, w1f, w2f);
        int tiles  = (n_tok + 31) / 32;
        int blocks = (tiles + 3) / 4;
        ffq_mfma_kernel<<<blocks, 256, 0, stream>>>(x, theta, w1f, w2f, b2, out,
                                                    n_tok);
    } else {
        int grid = (n_tok + 63) / 64;
        ffq_valu_kernel<<<grid, 256, 0, stream>>>(x, theta, w1, b1, w2, b2, out,
                                                  n_tok);
    }
}

// Round 9
// 41.557 us; speedup vs baseline: 4.1378x; 1.8035x over previous
//
#include <hip/hip_runtime.h>
#include <math.h>

#define FFN_DIM 4096
#define NCHUNK  128   // 4096 / 32

typedef _Float16 f16x8 __attribute__((ext_vector_type(8)));
typedef __fp16   h16x2 __attribute__((ext_vector_type(2)));
typedef float    f32x16 __attribute__((ext_vector_type(16)));
typedef float    f32x4  __attribute__((ext_vector_type(4)));

// ---------------------------------------------------------------------------
// Pre-kernel: build fp16 MFMA fragment tables in workspace.
//  w1f  [128][64][8] f16 (128KB): lanes 0-31 = W1 rows (k=0..7); lanes 32-63 =
//        {b1, 0,...} so the constant-1 column of q^T adds the bias (k=8).
//  w2f  [128][2][16][8] f16 (64KB): W2 rows permuted so GEMM1's C/D register
//        order feeds GEMM2's B operand directly: k -> f = (k&3)+8*((k>>2)&1)+4*(k>>3)
// (verified correct in round 7: absmax 3.9e-3)
// ---------------------------------------------------------------------------
__global__ void build_frags_kernel(const float* __restrict__ w1,
                                   const float* __restrict__ b1,
                                   const float* __restrict__ w2,
                                   _Float16* __restrict__ w1f,
                                   _Float16* __restrict__ w2f) {
    int i = blockIdx.x * 256 + threadIdx.x;
    if (i < NCHUNK * 64 * 8) {              // 65536
        int j    = i & 7;
        int lane = (i >> 3) & 63;
        int cc   = i >> 9;
        _Float16 v;
        if (lane < 32) v = (_Float16)w1[(cc * 32 + lane) * 8 + j];
        else           v = (j == 0) ? (_Float16)b1[cc * 32 + (lane & 31)]
                                    : (_Float16)0.0f;
        w1f[i] = v;
    }
    if (i < NCHUNK * 2 * 16 * 8) {          // 32768
        int j  = i & 7;
        int ci = (i >> 3) & 15;
        int c  = (i >> 7) & 1;
        int cc = i >> 8;
        int g = ci >> 3, e = ci & 7;
        int k = 8 * g + j;
        int fl = (k & 3) + 8 * ((k >> 2) & 1) + 4 * (k >> 3);
        int f = 32 * cc + 16 * c + fl;
        w2f[i] = (_Float16)w2[e * FFN_DIM + f];
    }
}

// ---------------------------------------------------------------------------
// Fused MFMA kernel, f-split for occupancy:
// one BLOCK = one 32-token tile; wave w handles chunks [32w, 32w+32);
// partial accumulators summed via LDS. grid = 2048 blocks -> 8 waves/SIMD.
// ---------------------------------------------------------------------------
__global__ __launch_bounds__(256, 8) void ffq_mfma_kernel(
    const float* __restrict__ x,
    const float* __restrict__ theta,
    const _Float16* __restrict__ w1f,   // [128][64][8]
    const _Float16* __restrict__ w2f,   // [128][2][16][8]
    const float* __restrict__ b2,
    float* __restrict__ out,
    int n_tok)
{
    __shared__ float part[4][64][4];    // 4KB

    const int tid  = threadIdx.x;
    const int lane = tid & 63;
    const int wave = tid >> 6;
    const int l31  = lane & 31;
    const int g    = lane >> 5;

    const int tb = blockIdx.x * 32;
    const float cth = cosf(theta[0]);

    // ---- B1 operand: q^T fragment (col = token = lane&31) ----
    f16x8 bq = {};
    if (g == 0) {
        int tok = tb + l31;
        int rt = tok < n_tok ? tok : (n_tok - 1);
        const f32x4* xp = (const f32x4*)(x + (size_t)rt * 8);
        f32x4 x0 = xp[0], x1 = xp[1];
        bq[0] = (_Float16)(cth * cosf(x0.x));
        bq[1] = (_Float16)(cth * cosf(x0.y));
        bq[2] = (_Float16)(cth * cosf(x0.z));
        bq[3] = (_Float16)(cth * cosf(x0.w));
        bq[4] = (_Float16)(cth * cosf(x1.x));
        bq[5] = (_Float16)(cth * cosf(x1.y));
        bq[6] = (_Float16)(cth * cosf(x1.z));
        bq[7] = (_Float16)(cth * cosf(x1.w));
    } else {
        bq[0] = (_Float16)1.0f;   // k=8 column: multiplies the b1 row of W1frag
    }

    f32x16 acc = {};
    const f32x16 zero16 = {};

    const bool a2on = (l31 < 8);
    const int  ci   = g * 8 + (lane & 7);
    const _Float16* a1p = w1f + (size_t)lane * 8;   // + cc*512
    const _Float16* a2p = w2f + (size_t)ci * 8;     // + cc*256 (+128 for half c=1)

    union U8 { f16x8 v; h16x2 p[4]; };

    const int c0 = wave * (NCHUNK / 4);
    const int c1 = c0 + (NCHUNK / 4);

    #pragma unroll 2
    for (int cc = c0; cc < c1; ++cc) {
        f16x8 A1 = *(const f16x8*)(a1p + (size_t)cc * 512);
        f16x8 A2a = {}, A2b = {};
        if (a2on) {
            A2a = *(const f16x8*)(a2p + (size_t)cc * 256);
            A2b = *(const f16x8*)(a2p + (size_t)cc * 256 + 128);
        }

        // GEMM1: h-tile (32 f x 32 tok), bias folded in via k=8
        f32x16 d1 = __builtin_amdgcn_mfma_f32_32x32x16_f16(A1, bq, zero16, 0, 0, 0);

        // relu + pack to fp16; register order already matches GEMM2's B layout
        U8 ua, ub;
        #pragma unroll
        for (int v = 0; v < 4; ++v) {
            ua.p[v] = __builtin_amdgcn_cvt_pkrtz(fmaxf(d1[2 * v], 0.0f),
                                                 fmaxf(d1[2 * v + 1], 0.0f));
            ub.p[v] = __builtin_amdgcn_cvt_pkrtz(fmaxf(d1[8 + 2 * v], 0.0f),
                                                 fmaxf(d1[8 + 2 * v + 1], 0.0f));
        }

        // GEMM2: two K=16 halves of the 32-f chunk
        acc = __builtin_amdgcn_mfma_f32_32x32x16_f16(A2a, ua.v, acc, 0, 0, 0);
        acc = __builtin_amdgcn_mfma_f32_32x32x16_f16(A2b, ub.v, acc, 0, 0, 0);
    }

    // rows e = 4g + r live in acc[0..3]; rows e>=8 are structurally zero
    #pragma unroll
    for (int r = 0; r < 4; ++r) part[wave][lane][r] = acc[r];
    __syncthreads();

    // 256 outputs per block (32 tok x 8 e), one per thread
    int t = tid >> 3, e = tid & 7;
    int gt = tb + t;
    if (gt < n_tok) {
        int sl = (e >> 2) * 32 + t;        // source lane for this (tok, e)
        int r  = e & 3;
        float s = part[0][sl][r] + part[1][sl][r]
                + part[2][sl][r] + part[3][sl][r] + b2[e];
        out[(size_t)gt * 8 + e] = s;
    }
}

// ---------------------------------------------------------------------------
// Fallback (ws too small): round-1 fp32 VALU kernel, direct w2 reads.
// ---------------------------------------------------------------------------
__global__ __launch_bounds__(256, 4) void ffq_valu_kernel(
    const float* __restrict__ x, const float* __restrict__ theta,
    const float* __restrict__ w1, const float* __restrict__ b1,
    const float* __restrict__ w2, const float* __restrict__ b2,
    float* __restrict__ out, int n_tok)
{
    __shared__ float part[4][64][9];
    const int tid = threadIdx.x;
    const int lane = tid & 63;
    const int wave = __builtin_amdgcn_readfirstlane(tid >> 6);
    const int tok = blockIdx.x * 64 + lane;
    const int rtok = tok < n_tok ? tok : n_tok - 1;
    const float cth = cosf(theta[0]);
    const f32x4* xv = (const f32x4*)(x + (size_t)rtok * 8);
    f32x4 x0 = xv[0], x1 = xv[1];
    float q[8];
    q[0]=cth*cosf(x0.x); q[1]=cth*cosf(x0.y); q[2]=cth*cosf(x0.z); q[3]=cth*cosf(x0.w);
    q[4]=cth*cosf(x1.x); q[5]=cth*cosf(x1.y); q[6]=cth*cosf(x1.z); q[7]=cth*cosf(x1.w);
    float acc[8];
    #pragma unroll
    for (int e = 0; e < 8; ++e) acc[e] = 0.0f;
    const int f0 = wave * (FFN_DIM / 4), f1 = f0 + (FFN_DIM / 4);
    #pragma unroll 2
    for (int f = f0; f < f1; ++f) {
        const f32x4* w1r = (const f32x4*)(w1 + (size_t)f * 8);
        f32x4 u0 = w1r[0], u1 = w1r[1];
        float h = b1[f];
        h = fmaf(u0.x,q[0],h); h = fmaf(u0.y,q[1],h); h = fmaf(u0.z,q[2],h); h = fmaf(u0.w,q[3],h);
        h = fmaf(u1.x,q[4],h); h = fmaf(u1.y,q[5],h); h = fmaf(u1.z,q[6],h); h = fmaf(u1.w,q[7],h);
        h = fmaxf(h, 0.0f);
        #pragma unroll
        for (int e = 0; e < 8; ++e) acc[e] = fmaf(h, w2[e * FFN_DIM + f], acc[e]);
    }
    #pragma unroll
    for (int e = 0; e < 8; ++e) part[wave][lane][e] = acc[e];
    __syncthreads();
    for (int i = tid; i < 64 * 8; i += 256) {
        int t = i >> 3, e = i & 7;
        int gt = blockIdx.x * 64 + t;
        if (gt < n_tok)
            out[(size_t)gt * 8 + e] = part[0][t][e] + part[1][t][e]
                                    + part[2][t][e] + part[3][t][e] + b2[e];
    }
}

extern "C" void kernel_launch(void* const* d_in, const int* in_sizes, int n_in,
                              void* d_out, int out_size, void* d_ws, size_t ws_size,
                              hipStream_t stream) {
    const float* x     = (const float*)d_in[0];
    const float* theta = (const float*)d_in[1];
    const float* w1    = (const float*)d_in[2];
    const float* b1    = (const float*)d_in[3];
    const float* w2    = (const float*)d_in[4];
    const float* b2    = (const float*)d_in[5];
    float* out = (float*)d_out;
    const int n_tok = out_size / 8;

    const size_t W1F_BYTES = (size_t)NCHUNK * 64 * 8 * sizeof(_Float16);  // 128KB
    const size_t W2F_BYTES = (size_t)NCHUNK * 2 * 16 * 8 * sizeof(_Float16); // 64KB

    if (ws_size >= W1F_BYTES + W2F_BYTES) {
        _Float16* w1f = (_Float16*)d_ws;
        _Float16* w2f = (_Float16*)((char*)d_ws + W1F_BYTES);
        build_frags_kernel<<<(NCHUNK * 64 * 8 + 255) / 256, 256, 0, stream>>>(
            w1, b1, w2, w1f, w2f);
        int blocks = (n_tok + 31) / 32;   // one 32-token tile per block
        ffq_mfma_kernel<<<blocks, 256, 0, stream>>>(x, theta, w1f, w2f, b2, out,
                                                    n_tok);
    } else {
        int grid = (n_tok + 63) / 64;
        ffq_valu_kernel<<<grid, 256, 0, stream>>>(x, theta, w1, b1, w2, b2, out,
                                                  n_tok);
    }
}

// Round 10
// 38.981 us; speedup vs baseline: 4.4113x; 1.0661x over previous
//
#include <hip/hip_runtime.h>
#include <math.h>

#define FFN_DIM 4096
#define NCHUNK  128   // 4096 / 32

typedef _Float16 f16x8 __attribute__((ext_vector_type(8)));
typedef __fp16   h16x2 __attribute__((ext_vector_type(2)));
typedef float    f32x16 __attribute__((ext_vector_type(16)));
typedef float    f32x4  __attribute__((ext_vector_type(4)));

// ---------------------------------------------------------------------------
// Pre-kernel: build fp16 MFMA fragment tables in workspace.
//  w1f  [128][64][8] f16 (128KB): lanes 0-31 = W1 rows (k=0..7); lanes 32-63 =
//        {b1, 0,...} so the constant-1 column of q^T adds the bias (k=8).
//  w2f  [128][2][16][8] f16 (64KB): W2 rows permuted so GEMM1's C/D register
//        order feeds GEMM2's B operand directly: k -> f = (k&3)+8*((k>>2)&1)+4*(k>>3)
// (verified correct in rounds 7/9: absmax 3.9e-3)
// ---------------------------------------------------------------------------
__global__ void build_frags_kernel(const float* __restrict__ w1,
                                   const float* __restrict__ b1,
                                   const float* __restrict__ w2,
                                   _Float16* __restrict__ w1f,
                                   _Float16* __restrict__ w2f) {
    int i = blockIdx.x * 256 + threadIdx.x;
    if (i < NCHUNK * 64 * 8) {              // 65536
        int j    = i & 7;
        int lane = (i >> 3) & 63;
        int cc   = i >> 9;
        _Float16 v;
        if (lane < 32) v = (_Float16)w1[(cc * 32 + lane) * 8 + j];
        else           v = (j == 0) ? (_Float16)b1[cc * 32 + (lane & 31)]
                                    : (_Float16)0.0f;
        w1f[i] = v;
    }
    if (i < NCHUNK * 2 * 16 * 8) {          // 32768
        int j  = i & 7;
        int ci = (i >> 3) & 15;
        int c  = (i >> 7) & 1;
        int cc = i >> 8;
        int g = ci >> 3, e = ci & 7;
        int k = 8 * g + j;
        int fl = (k & 3) + 8 * ((k >> 2) & 1) + 4 * (k >> 3);
        int f = 32 * cc + 16 * c + fl;
        w2f[i] = (_Float16)w2[e * FFN_DIM + f];
    }
}

// ---------------------------------------------------------------------------
// Fused MFMA kernel, f-split across 4 waves, 6 waves/SIMD occupancy.
// one BLOCK = one 32-token tile; wave w handles chunks [32w, 32w+32);
// partial accumulators summed via LDS.
// A2 loads are unconditional: lanes 8..31 duplicate rows 0..7, producing
// duplicate D-rows 8..31 that are never read (acc[0..3] = rows 0..7 only).
// ---------------------------------------------------------------------------
__global__ __launch_bounds__(256, 6) void ffq_mfma_kernel(
    const float* __restrict__ x,
    const float* __restrict__ theta,
    const _Float16* __restrict__ w1f,   // [128][64][8]
    const _Float16* __restrict__ w2f,   // [128][2][16][8]
    const float* __restrict__ b2,
    float* __restrict__ out,
    int n_tok)
{
    __shared__ float part[4][64][4];    // 4KB

    const int tid  = threadIdx.x;
    const int lane = tid & 63;
    const int wave = tid >> 6;
    const int l31  = lane & 31;
    const int g    = lane >> 5;

    const int tb = blockIdx.x * 32;
    const float cth = cosf(theta[0]);

    // ---- B1 operand: q^T fragment (col = token = lane&31) ----
    f16x8 bq = {};
    if (g == 0) {
        int tok = tb + l31;
        int rt = tok < n_tok ? tok : (n_tok - 1);
        const f32x4* xp = (const f32x4*)(x + (size_t)rt * 8);
        f32x4 x0 = xp[0], x1 = xp[1];
        bq[0] = (_Float16)(cth * cosf(x0.x));
        bq[1] = (_Float16)(cth * cosf(x0.y));
        bq[2] = (_Float16)(cth * cosf(x0.z));
        bq[3] = (_Float16)(cth * cosf(x0.w));
        bq[4] = (_Float16)(cth * cosf(x1.x));
        bq[5] = (_Float16)(cth * cosf(x1.y));
        bq[6] = (_Float16)(cth * cosf(x1.z));
        bq[7] = (_Float16)(cth * cosf(x1.w));
    } else {
        bq[0] = (_Float16)1.0f;   // k=8 column: multiplies the b1 row of W1frag
    }

    f32x16 acc = {};
    const f32x16 zero16 = {};

    // A-operand row for G2 = lane&31; table holds rows 0..7 (e) x 2 k-halves.
    // All lanes load entry (g, l31&7): rows 8..31 become duplicates (ignored).
    const int  ci   = g * 8 + (l31 & 7);
    const _Float16* a1p = w1f + (size_t)lane * 8;   // + cc*512
    const _Float16* a2p = w2f + (size_t)ci * 8;     // + cc*256 (+128 for half c=1)

    union U8 { f16x8 v; h16x2 p[4]; };
    const h16x2 hz = {(__fp16)0.0f, (__fp16)0.0f};

    const int c0 = wave * (NCHUNK / 4);
    const int c1 = c0 + (NCHUNK / 4);

    #pragma unroll 2
    for (int cc = c0; cc < c1; ++cc) {
        f16x8 A1  = *(const f16x8*)(a1p + (size_t)cc * 512);
        f16x8 A2a = *(const f16x8*)(a2p + (size_t)cc * 256);
        f16x8 A2b = *(const f16x8*)(a2p + (size_t)cc * 256 + 128);

        // GEMM1: h-tile (32 f x 32 tok), bias folded in via k=8
        f32x16 d1 = __builtin_amdgcn_mfma_f32_32x32x16_f16(A1, bq, zero16, 0, 0, 0);

        // pack to fp16 then relu via v_pk_max_f16 (16 VALU ops total)
        U8 ua, ub;
        #pragma unroll
        for (int v = 0; v < 4; ++v) {
            ua.p[v] = __builtin_amdgcn_cvt_pkrtz(d1[2 * v],     d1[2 * v + 1]);
            ub.p[v] = __builtin_amdgcn_cvt_pkrtz(d1[8 + 2 * v], d1[8 + 2 * v + 1]);
        }
        #pragma unroll
        for (int v = 0; v < 4; ++v) {
            ua.p[v] = __builtin_elementwise_max(ua.p[v], hz);
            ub.p[v] = __builtin_elementwise_max(ub.p[v], hz);
        }

        // GEMM2: two K=16 halves of the 32-f chunk
        acc = __builtin_amdgcn_mfma_f32_32x32x16_f16(A2a, ua.v, acc, 0, 0, 0);
        acc = __builtin_amdgcn_mfma_f32_32x32x16_f16(A2b, ub.v, acc, 0, 0, 0);
    }

    // rows e = 4g + r live in acc[0..3]
    #pragma unroll
    for (int r = 0; r < 4; ++r) part[wave][lane][r] = acc[r];
    __syncthreads();

    // 256 outputs per block (32 tok x 8 e), one per thread
    int t = tid >> 3, e = tid & 7;
    int gt = tb + t;
    if (gt < n_tok) {
        int sl = (e >> 2) * 32 + t;        // source lane for this (tok, e)
        int r  = e & 3;
        float s = part[0][sl][r] + part[1][sl][r]
                + part[2][sl][r] + part[3][sl][r] + b2[e];
        out[(size_t)gt * 8 + e] = s;
    }
}

// ---------------------------------------------------------------------------
// Fallback (ws too small): round-1 fp32 VALU kernel, direct w2 reads.
// ---------------------------------------------------------------------------
__global__ __launch_bounds__(256, 4) void ffq_valu_kernel(
    const float* __restrict__ x, const float* __restrict__ theta,
    const float* __restrict__ w1, const float* __restrict__ b1,
    const float* __restrict__ w2, const float* __restrict__ b2,
    float* __restrict__ out, int n_tok)
{
    __shared__ float part[4][64][9];
    const int tid = threadIdx.x;
    const int lane = tid & 63;
    const int wave = __builtin_amdgcn_readfirstlane(tid >> 6);
    const int tok = blockIdx.x * 64 + lane;
    const int rtok = tok < n_tok ? tok : n_tok - 1;
    const float cth = cosf(theta[0]);
    const f32x4* xv = (const f32x4*)(x + (size_t)rtok * 8);
    f32x4 x0 = xv[0], x1 = xv[1];
    float q[8];
    q[0]=cth*cosf(x0.x); q[1]=cth*cosf(x0.y); q[2]=cth*cosf(x0.z); q[3]=cth*cosf(x0.w);
    q[4]=cth*cosf(x1.x); q[5]=cth*cosf(x1.y); q[6]=cth*cosf(x1.z); q[7]=cth*cosf(x1.w);
    float acc[8];
    #pragma unroll
    for (int e = 0; e < 8; ++e) acc[e] = 0.0f;
    const int f0 = wave * (FFN_DIM / 4), f1 = f0 + (FFN_DIM / 4);
    #pragma unroll 2
    for (int f = f0; f < f1; ++f) {
        const f32x4* w1r = (const f32x4*)(w1 + (size_t)f * 8);
        f32x4 u0 = w1r[0], u1 = w1r[1];
        float h = b1[f];
        h = fmaf(u0.x,q[0],h); h = fmaf(u0.y,q[1],h); h = fmaf(u0.z,q[2],h); h = fmaf(u0.w,q[3],h);
        h = fmaf(u1.x,q[4],h); h = fmaf(u1.y,q[5],h); h = fmaf(u1.z,q[6],h); h = fmaf(u1.w,q[7],h);
        h = fmaxf(h, 0.0f);
        #pragma unroll
        for (int e = 0; e < 8; ++e) acc[e] = fmaf(h, w2[e * FFN_DIM + f], acc[e]);
    }
    #pragma unroll
    for (int e = 0; e < 8; ++e) part[wave][lane][e] = acc[e];
    __syncthreads();
    for (int i = tid; i < 64 * 8; i += 256) {
        int t = i >> 3, e = i & 7;
        int gt = blockIdx.x * 64 + t;
        if (gt < n_tok)
            out[(size_t)gt * 8 + e] = part[0][t][e] + part[1][t][e]
                                    + part[2][t][e] + part[3][t][e] + b2[e];
    }
}

extern "C" void kernel_launch(void* const* d_in, const int* in_sizes, int n_in,
                              void* d_out, int out_size, void* d_ws, size_t ws_size,
                              hipStream_t stream) {
    const float* x     = (const float*)d_in[0];
    const float* theta = (const float*)d_in[1];
    const float* w1    = (const float*)d_in[2];
    const float* b1    = (const float*)d_in[3];
    const float* w2    = (const float*)d_in[4];
    const float* b2    = (const float*)d_in[5];
    float* out = (float*)d_out;
    const int n_tok = out_size / 8;

    const size_t W1F_BYTES = (size_t)NCHUNK * 64 * 8 * sizeof(_Float16);  // 128KB
    const size_t W2F_BYTES = (size_t)NCHUNK * 2 * 16 * 8 * sizeof(_Float16); // 64KB

    if (ws_size >= W1F_BYTES + W2F_BYTES) {
        _Float16* w1f = (_Float16*)d_ws;
        _Float16* w2f = (_Float16*)((char*)d_ws + W1F_BYTES);
        build_frags_kernel<<<(NCHUNK * 64 * 8 + 255) / 256, 256, 0, stream>>>(
            w1, b1, w2, w1f, w2f);
        int blocks = (n_tok + 31) / 32;   // one 32-token tile per block
        ffq_mfma_kernel<<<blocks, 256, 0, stream>>>(x, theta, w1f, w2f, b2, out,
                                                    n_tok);
    } else {
        int grid = (n_tok + 63) / 64;
        ffq_valu_kernel<<<grid, 256, 0, stream>>>(x, theta, w1, b1, w2, b2, out,
                                                  n_tok);
    }
}

// Round 12
// 35.465 us; speedup vs baseline: 4.8486x; 1.0991x over previous
//
#include <hip/hip_runtime.h>
#include <math.h>

#define FFN_DIM 4096
#define NCHUNK  128   // 4096 / 32

typedef _Float16 f16x8 __attribute__((ext_vector_type(8)));
typedef __fp16   h16x2 __attribute__((ext_vector_type(2)));
typedef float    f32x16 __attribute__((ext_vector_type(16)));
typedef float    f32x4  __attribute__((ext_vector_type(4)));

// ---------------------------------------------------------------------------
// Pre-kernel: build fp16 MFMA fragment tables in workspace.
//  w1f  [128][64][8] f16 (128KB): lanes 0-31 = W1 rows (k=0..7); lanes 32-63 =
//        {b1, 0,...} so the constant-1 column of q^T adds the bias (k=8).
//  w2f  [128][2][16][8] f16 (64KB): W2 rows permuted so GEMM1's C/D register
//        order feeds GEMM2's B operand directly: k -> f = (k&3)+8*((k>>2)&1)+4*(k>>3)
// (verified correct in rounds 7/9/10: absmax 3.9e-3)
// ---------------------------------------------------------------------------
__global__ void build_frags_kernel(const float* __restrict__ w1,
                                   const float* __restrict__ b1,
                                   const float* __restrict__ w2,
                                   _Float16* __restrict__ w1f,
                                   _Float16* __restrict__ w2f) {
    int i = blockIdx.x * 256 + threadIdx.x;
    if (i < NCHUNK * 64 * 8) {              // 65536
        int j    = i & 7;
        int lane = (i >> 3) & 63;
        int cc   = i >> 9;
        _Float16 v;
        if (lane < 32) v = (_Float16)w1[(cc * 32 + lane) * 8 + j];
        else           v = (j == 0) ? (_Float16)b1[cc * 32 + (lane & 31)]
                                    : (_Float16)0.0f;
        w1f[i] = v;
    }
    if (i < NCHUNK * 2 * 16 * 8) {          // 32768
        int j  = i & 7;
        int ci = (i >> 3) & 15;
        int c  = (i >> 7) & 1;
        int cc = i >> 8;
        int g = ci >> 3, e = ci & 7;
        int k = 8 * g + j;
        int fl = (k & 3) + 8 * ((k >> 2) & 1) + 4 * (k >> 3);
        int f = 32 * cc + 16 * c + fl;
        w2f[i] = (_Float16)w2[e * FFN_DIM + f];
    }
}

// ---------------------------------------------------------------------------
// Fused MFMA kernel: one BLOCK = TWO 32-token tiles (64 tok); 4 waves f-split
// (wave w owns chunks [32w,32w+32)); weight fragments loaded ONCE per chunk
// feed both tiles (2x G1, 4x G2) -> dual independent dep chains per wave.
// Partial accumulators summed via LDS.
// ---------------------------------------------------------------------------
__global__ __launch_bounds__(256, 4) void ffq_mfma_kernel(
    const float* __restrict__ x,
    const float* __restrict__ theta,
    const _Float16* __restrict__ w1f,   // [128][64][8]
    const _Float16* __restrict__ w2f,   // [128][2][16][8]
    const float* __restrict__ b2,
    float* __restrict__ out,
    int n_tok)
{
    __shared__ float part[4][2][64][4];    // 8KB

    const int tid  = threadIdx.x;
    const int lane = tid & 63;
    const int wave = tid >> 6;
    const int l31  = lane & 31;
    const int g    = lane >> 5;

    const int tb = blockIdx.x * 64;
    const float cth = cosf(theta[0]);

    // ---- B1 operands: q^T fragments for the two tiles (col = tok = lane&31)
    f16x8 bq0 = {}, bq1 = {};
    if (g == 0) {
        int t0 = tb + l31;
        int r0 = t0 < n_tok ? t0 : (n_tok - 1);
        const f32x4* xp0 = (const f32x4*)(x + (size_t)r0 * 8);
        f32x4 a0 = xp0[0], a1 = xp0[1];
        bq0[0] = (_Float16)(cth * cosf(a0.x));
        bq0[1] = (_Float16)(cth * cosf(a0.y));
        bq0[2] = (_Float16)(cth * cosf(a0.z));
        bq0[3] = (_Float16)(cth * cosf(a0.w));
        bq0[4] = (_Float16)(cth * cosf(a1.x));
        bq0[5] = (_Float16)(cth * cosf(a1.y));
        bq0[6] = (_Float16)(cth * cosf(a1.z));
        bq0[7] = (_Float16)(cth * cosf(a1.w));
        int t1 = tb + 32 + l31;
        int r1 = t1 < n_tok ? t1 : (n_tok - 1);
        const f32x4* xp1 = (const f32x4*)(x + (size_t)r1 * 8);
        f32x4 b0 = xp1[0], b1v = xp1[1];
        bq1[0] = (_Float16)(cth * cosf(b0.x));
        bq1[1] = (_Float16)(cth * cosf(b0.y));
        bq1[2] = (_Float16)(cth * cosf(b0.z));
        bq1[3] = (_Float16)(cth * cosf(b0.w));
        bq1[4] = (_Float16)(cth * cosf(b1v.x));
        bq1[5] = (_Float16)(cth * cosf(b1v.y));
        bq1[6] = (_Float16)(cth * cosf(b1v.z));
        bq1[7] = (_Float16)(cth * cosf(b1v.w));
    } else {
        bq0[0] = (_Float16)1.0f;   // k=8 column: multiplies the b1 row of W1frag
        bq1[0] = (_Float16)1.0f;
    }

    f32x16 acc0 = {}, acc1 = {};
    const f32x16 zero16 = {};

    // A-operand row for G2 = lane&31; table holds rows 0..7 (e) x 2 k-halves.
    // All lanes load entry (g, l31&7): rows 8..31 become duplicates (ignored).
    const int  ci   = g * 8 + (l31 & 7);
    const _Float16* a1p = w1f + (size_t)lane * 8;   // + cc*512
    const _Float16* a2p = w2f + (size_t)ci * 8;     // + cc*256 (+128 for half c=1)

    union U8 { f16x8 v; h16x2 p[4]; };
    const h16x2 hz = {(__fp16)0.0f, (__fp16)0.0f};

    const int c0 = wave * (NCHUNK / 4);
    const int c1 = c0 + (NCHUNK / 4);

    for (int cc = c0; cc < c1; ++cc) {
        f16x8 A1  = *(const f16x8*)(a1p + (size_t)cc * 512);
        f16x8 A2a = *(const f16x8*)(a2p + (size_t)cc * 256);
        f16x8 A2b = *(const f16x8*)(a2p + (size_t)cc * 256 + 128);

        // GEMM1 for both tiles (shared A1)
        f32x16 d1a = __builtin_amdgcn_mfma_f32_32x32x16_f16(A1, bq0, zero16, 0, 0, 0);
        f32x16 d1b = __builtin_amdgcn_mfma_f32_32x32x16_f16(A1, bq1, zero16, 0, 0, 0);

        // pack to fp16 + relu via v_pk_max_f16
        U8 ua0, ub0, ua1, ub1;
        #pragma unroll
        for (int v = 0; v < 4; ++v) {
            ua0.p[v] = __builtin_amdgcn_cvt_pkrtz(d1a[2 * v],     d1a[2 * v + 1]);
            ub0.p[v] = __builtin_amdgcn_cvt_pkrtz(d1a[8 + 2 * v], d1a[8 + 2 * v + 1]);
            ua1.p[v] = __builtin_amdgcn_cvt_pkrtz(d1b[2 * v],     d1b[2 * v + 1]);
            ub1.p[v] = __builtin_amdgcn_cvt_pkrtz(d1b[8 + 2 * v], d1b[8 + 2 * v + 1]);
        }
        #pragma unroll
        for (int v = 0; v < 4; ++v) {
            ua0.p[v] = __builtin_elementwise_max(ua0.p[v], hz);
            ub0.p[v] = __builtin_elementwise_max(ub0.p[v], hz);
            ua1.p[v] = __builtin_elementwise_max(ua1.p[v], hz);
            ub1.p[v] = __builtin_elementwise_max(ub1.p[v], hz);
        }

        // GEMM2 for both tiles (shared A2a/A2b)
        acc0 = __builtin_amdgcn_mfma_f32_32x32x16_f16(A2a, ua0.v, acc0, 0, 0, 0);
        acc0 = __builtin_amdgcn_mfma_f32_32x32x16_f16(A2b, ub0.v, acc0, 0, 0, 0);
        acc1 = __builtin_amdgcn_mfma_f32_32x32x16_f16(A2a, ua1.v, acc1, 0, 0, 0);
        acc1 = __builtin_amdgcn_mfma_f32_32x32x16_f16(A2b, ub1.v, acc1, 0, 0, 0);
    }

    // rows e = 4g + r live in acc[0..3]
    #pragma unroll
    for (int r = 0; r < 4; ++r) {
        part[wave][0][lane][r] = acc0[r];
        part[wave][1][lane][r] = acc1[r];
    }
    __syncthreads();

    // 512 outputs per block (64 tok x 8 e), 2 per thread
    for (int i = tid; i < 64 * 8; i += 256) {
        int t = i >> 3, e = i & 7;
        int gt = tb + t;
        if (gt < n_tok) {
            int tt = t >> 5;                // which tile
            int tl = t & 31;
            int sl = (e >> 2) * 32 + tl;    // source lane for this (tok, e)
            int r  = e & 3;
            float s = part[0][tt][sl][r] + part[1][tt][sl][r]
                    + part[2][tt][sl][r] + part[3][tt][sl][r] + b2[e];
            out[(size_t)gt * 8 + e] = s;
        }
    }
}

// ---------------------------------------------------------------------------
// Fallback (ws too small): round-1 fp32 VALU kernel, direct w2 reads.
// ---------------------------------------------------------------------------
__global__ __launch_bounds__(256, 4) void ffq_valu_kernel(
    const float* __restrict__ x, const float* __restrict__ theta,
    const float* __restrict__ w1, const float* __restrict__ b1,
    const float* __restrict__ w2, const float* __restrict__ b2,
    float* __restrict__ out, int n_tok)
{
    __shared__ float part[4][64][9];
    const int tid = threadIdx.x;
    const int lane = tid & 63;
    const int wave = __builtin_amdgcn_readfirstlane(tid >> 6);
    const int tok = blockIdx.x * 64 + lane;
    const int rtok = tok < n_tok ? tok : n_tok - 1;
    const float cth = cosf(theta[0]);
    const f32x4* xv = (const f32x4*)(x + (size_t)rtok * 8);
    f32x4 x0 = xv[0], x1 = xv[1];
    float q[8];
    q[0]=cth*cosf(x0.x); q[1]=cth*cosf(x0.y); q[2]=cth*cosf(x0.z); q[3]=cth*cosf(x0.w);
    q[4]=cth*cosf(x1.x); q[5]=cth*cosf(x1.y); q[6]=cth*cosf(x1.z); q[7]=cth*cosf(x1.w);
    float acc[8];
    #pragma unroll
    for (int e = 0; e < 8; ++e) acc[e] = 0.0f;
    const int f0 = wave * (FFN_DIM / 4), f1 = f0 + (FFN_DIM / 4);
    #pragma unroll 2
    for (int f = f0; f < f1; ++f) {
        const f32x4* w1r = (const f32x4*)(w1 + (size_t)f * 8);
        f32x4 u0 = w1r[0], u1 = w1r[1];
        float h = b1[f];
        h = fmaf(u0.x,q[0],h); h = fmaf(u0.y,q[1],h); h = fmaf(u0.z,q[2],h); h = fmaf(u0.w,q[3],h);
        h = fmaf(u1.x,q[4],h); h = fmaf(u1.y,q[5],h); h = fmaf(u1.z,q[6],h); h = fmaf(u1.w,q[7],h);
        h = fmaxf(h, 0.0f);
        #pragma unroll
        for (int e = 0; e < 8; ++e) acc[e] = fmaf(h, w2[e * FFN_DIM + f], acc[e]);
    }
    #pragma unroll
    for (int e = 0; e < 8; ++e) part[wave][lane][e] = acc[e];
    __syncthreads();
    for (int i = tid; i < 64 * 8; i += 256) {
        int t = i >> 3, e = i & 7;
        int gt = blockIdx.x * 64 + t;
        if (gt < n_tok)
            out[(size_t)gt * 8 + e] = part[0][t][e] + part[1][t][e]
                                    + part[2][t][e] + part[3][t][e] + b2[e];
    }
}

extern "C" void kernel_launch(void* const* d_in, const int* in_sizes, int n_in,
                              void* d_out, int out_size, void* d_ws, size_t ws_size,
                              hipStream_t stream) {
    const float* x     = (const float*)d_in[0];
    const float* theta = (const float*)d_in[1];
    const float* w1    = (const float*)d_in[2];
    const float* b1    = (const float*)d_in[3];
    const float* w2    = (const float*)d_in[4];
    const float* b2    = (const float*)d_in[5];
    float* out = (float*)d_out;
    const int n_tok = out_size / 8;

    const size_t W1F_BYTES = (size_t)NCHUNK * 64 * 8 * sizeof(_Float16);  // 128KB
    const size_t W2F_BYTES = (size_t)NCHUNK * 2 * 16 * 8 * sizeof(_Float16); // 64KB

    if (ws_size >= W1F_BYTES + W2F_BYTES) {
        _Float16* w1f = (_Float16*)d_ws;
        _Float16* w2f = (_Float16*)((char*)d_ws + W1F_BYTES);
        build_frags_kernel<<<(NCHUNK * 64 * 8 + 255) / 256, 256, 0, stream>>>(
            w1, b1, w2, w1f, w2f);
        int blocks = (n_tok + 63) / 64;   // two 32-token tiles per block
        ffq_mfma_kernel<<<blocks, 256, 0, stream>>>(x, theta, w1f, w2f, b2, out,
                                                    n_tok);
    } else {
        int grid = (n_tok + 63) / 64;
        ffq_valu_kernel<<<grid, 256, 0, stream>>>(x, theta, w1, b1, w2, b2, out,
                                                  n_tok);
    }
}